// Round 10
// baseline (2093.591 us; speedup 1.0000x reference)
//
#include <hip/hip_runtime.h>
#include <math.h>
#include <stdint.h>

#define B 1024
#define H 512
#define E 256
#define L 128
#define LE (L*E)   // 32768

typedef _Float16 f16;
typedef _Float16 f16x8 __attribute__((ext_vector_type(8)));
typedef _Float16 f16x4 __attribute__((ext_vector_type(4)));
typedef float f32x4 __attribute__((ext_vector_type(4)));
typedef const __attribute__((address_space(1))) uint32_t gu32;
typedef __attribute__((address_space(3))) uint32_t lu32;

// ---------------------------------------------------------------------------
// Persistent state in module device globals. Everything rewritten every call.
// ---------------------------------------------------------------------------
__device__ __align__(16) f16 g_Xs[128*16*4*4096];   // X images [t:128 pad][mt16][kt:4] 64x64
__device__ __align__(16) f16 g_Hh[128*16*8*4096];   // h(t) images, t=0..127 (134 MB)
__device__ __align__(16) f16 g_Ws[16*12*8192];      // gates W' [itile:16][kt:12] 128x64
__device__ __align__(16) f16 g_W1s[8*8192];         // W1' [kt:8] 128x64
__device__ __align__(16) f16 g_W2s[2*8192];         // W2' [kt:2] 128x64
__device__ __align__(16) f16 g_W3s[4*8192];         // W3' [nh:2][kt:2] 128x64
__device__ __align__(16) float g_bsum[2048];        // b_ih+b_hh, n=j*4+g order

// Per-group barrier state: 8 independent 32-block groups, one cacheline each.
struct __align__(128) Bar { unsigned int cnt; unsigned int phase; unsigned int pad[30]; };
__device__ Bar g_bars[8];

// Round-9 validated split barrier: arrival releases h stores; wait deferred,
// relaxed spin + single acquire at exit.
__device__ __forceinline__ void bar_arrive(int g, unsigned int target) {
    __syncthreads();
    if (threadIdx.x == 0) {
        unsigned int prev = __hip_atomic_fetch_add(&g_bars[g].cnt, 1u,
                              __ATOMIC_ACQ_REL, __HIP_MEMORY_SCOPE_AGENT);
        if (prev == 31u) {
            __hip_atomic_store(&g_bars[g].cnt, 0u, __ATOMIC_RELAXED, __HIP_MEMORY_SCOPE_AGENT);
            __hip_atomic_store(&g_bars[g].phase, target, __ATOMIC_RELEASE, __HIP_MEMORY_SCOPE_AGENT);
        }
    }
}
__device__ __forceinline__ void bar_wait(int g, unsigned int target) {
    if (threadIdx.x == 0) {
        while (__hip_atomic_load(&g_bars[g].phase, __ATOMIC_RELAXED,
                                 __HIP_MEMORY_SCOPE_AGENT) < target)
            __builtin_amdgcn_s_sleep(1);
        (void)__hip_atomic_load(&g_bars[g].phase, __ATOMIC_ACQUIRE,
                                __HIP_MEMORY_SCOPE_AGENT);
    }
    __syncthreads();
}

__device__ __forceinline__ float fsigm(float x) {
    return __builtin_amdgcn_rcpf(1.0f + __expf(-x));
}
__device__ __forceinline__ float ftanh(float x) {
    return 2.0f * __builtin_amdgcn_rcpf(1.0f + __expf(-2.0f * x)) - 1.0f;
}

// ---------------------------------------------------------------------------
// conv_w: gates W' fp16 tile images (gate-interleaved n=j*4+g) + bias sums
// ---------------------------------------------------------------------------
__global__ __launch_bounds__(256) void conv_w(
    const float* __restrict__ W_ih, const float* __restrict__ W_hh,
    const float* __restrict__ b_ih, const float* __restrict__ b_hh)
{
    int gid = blockIdx.x*256 + threadIdx.x;   // 196608
    int kb  = gid & 7;
    int r1  = gid >> 3;
    int row = r1 & 127;
    int r2  = r1 >> 7;
    int kt  = r2 % 12;
    int nt  = r2 / 12;
    int n = nt*128 + row;
    int g = n & 3, j = n >> 2;
    int wrow = g*512 + j;
    int k = kt*64 + kb*8;
    const float* src = (k < 256) ? (W_ih + wrow*256 + k)
                                 : (W_hh + wrow*512 + (k - 256));
    f16x8 v;
    #pragma unroll
    for (int e = 0; e < 8; ++e) v[e] = (f16)src[e];
    char* dst = (char*)g_Ws + (size_t)(nt*12 + kt)*16384
              + row*128 + ((kb*16) ^ ((row & 7) << 4));
    *(f16x8*)dst = v;
    if (gid < 2048) {
        int gg = gid & 3, jj = gid >> 2;
        g_bsum[gid] = b_ih[gg*512 + jj] + b_hh[gg*512 + jj];
    }
}

// ---------------------------------------------------------------------------
// conv_mlp: W1/W2/W3 fp16 tile images
// ---------------------------------------------------------------------------
__global__ __launch_bounds__(256) void conv_mlp(
    const float* __restrict__ W1, const float* __restrict__ W2,
    const float* __restrict__ W3)
{
    int gid = blockIdx.x*256 + threadIdx.x;   // 14336
    if (gid < 8192) {                         // W1 (128,512) -> 8 tiles
        int s = gid;
        int kb = s & 7, row = (s >> 3) & 127, kt = s >> 10;
        const float* src = W1 + row*512 + kt*64 + kb*8;
        f16x8 v;
        #pragma unroll
        for (int e = 0; e < 8; ++e) v[e] = (f16)src[e];
        char* dst = (char*)g_W1s + (size_t)kt*16384
                  + row*128 + ((kb*16) ^ ((row & 7) << 4));
        *(f16x8*)dst = v;
    } else if (gid < 10240) {                 // W2 (128,128) -> 2 tiles
        int s = gid - 8192;
        int kb = s & 7, row = (s >> 3) & 127, kt = s >> 10;
        const float* src = W2 + row*128 + kt*64 + kb*8;
        f16x8 v;
        #pragma unroll
        for (int e = 0; e < 8; ++e) v[e] = (f16)src[e];
        char* dst = (char*)g_W2s + (size_t)kt*16384
                  + row*128 + ((kb*16) ^ ((row & 7) << 4));
        *(f16x8*)dst = v;
    } else if (gid < 14336) {                 // W3 (256,128) -> [nh:2][kt:2]
        int s = gid - 10240;
        int kb = s & 7, r256 = (s >> 3) & 255, kt = s >> 11;
        int nh = r256 >> 7, row = r256 & 127;
        const float* src = W3 + r256*128 + kt*64 + kb*8;
        f16x8 v;
        #pragma unroll
        for (int e = 0; e < 8; ++e) v[e] = (f16)src[e];
        char* dst = (char*)g_W3s + (size_t)(nh*2 + kt)*16384
                  + row*128 + ((kb*16) ^ ((row & 7) << 4));
        *(f16x8*)dst = v;
    }
}

// ---------------------------------------------------------------------------
// conv_x: X fp16 tile images (coalesced: 32 consecutive lanes = 1 KB)
// ---------------------------------------------------------------------------
__global__ __launch_bounds__(256) void conv_x(const float* __restrict__ padded)
{
    int gid = blockIdx.x*256 + threadIdx.x;   // 127*1024*32 = 4161536 exact
    int kq = gid & 31;
    int b  = (gid >> 5) & 1023;
    int t  = gid >> 15;
    const float* src = padded + (size_t)b*LE + t*E + kq*8;
    float4 v0 = *(const float4*)src;
    float4 v1 = *(const float4*)(src + 4);
    f16x8 v;
    v[0]=(f16)v0.x; v[1]=(f16)v0.y; v[2]=(f16)v0.z; v[3]=(f16)v0.w;
    v[4]=(f16)v1.x; v[5]=(f16)v1.y; v[6]=(f16)v1.z; v[7]=(f16)v1.w;
    int kt = kq >> 3, kb = kq & 7;
    int row = b & 63, mt16 = b >> 6;
    char* dst = (char*)g_Xs + (size_t)((t*16 + mt16)*4 + kt)*8192
              + row*128 + ((kb*16) ^ ((row & 7) << 4));
    *(f16x8*)dst = v;
}

// ---------------------------------------------------------------------------
// init: g_Hh[0] <- hidden image, out row 0 <- one-hot, barrier reset
// ---------------------------------------------------------------------------
__global__ __launch_bounds__(256) void init_kernel(
    const float* __restrict__ hidden, float* __restrict__ out)
{
    int i = blockIdx.x * 256 + threadIdx.x;
    if (i < 8) { g_bars[i].cnt = 0u; g_bars[i].phase = 0u; }
    if (i < B*H) {
        float hv = hidden[i];
        int b = i >> 9, j = i & 511;
        int mt = b >> 6, row = b & 63, kt = j >> 6, kk = j & 63;
        char* dst = (char*)g_Hh + (size_t)(mt*8 + kt)*8192
                  + row*128 + ((kk*2) ^ ((row & 7) << 4));
        *(f16*)dst = (f16)hv;
    }
    if (i < B*E) {
        int b = i >> 8, e = i & 255;
        out[b*LE + e] = (e == 0) ? 1.0f : 0.0f;
    }
}

// ---------------------------------------------------------------------------
// step_all: persistent gates recurrence, 8 groups of 32 blocks.
// NOW 512 threads (8 waves = 2/SIMD) for latency hiding; waves tile 4Mx2N
// (wave = 32x32, 2x2 frags). B (96 KB) persistent; A in 4 rotating 16 KB
// slots -> ONE barrier per kt (restage slot (kt+3)%4, last read kt-1).
// vmcnt: kt2->2, kt3->0 (drain before group-wait), else 4. X prefetch
// unconditional (g_Xs padded to 128 t). LDS = 96+64 = 160 KiB exactly.
// ---------------------------------------------------------------------------
__global__ __launch_bounds__(512, 2) void step_all()
{
    __shared__ __align__(16) char lds[163840];
    char* Bb = lds;                                   // 12 x 8192 persistent B
    char* As = lds + 98304;                           // 4 x 16384 A slots
    f16 (*Hs)[16] = (f16 (*)[16])(lds + 98304 + 3*16384);  // aliases slot3

    const int tid  = threadIdx.x;
    const int lane = tid & 63;
    const int wv   = tid >> 6;          // 0..7
    const int mg   = wv >> 1;           // 0..3 (32-row strip)
    const int ng   = wv & 1;            // 0..1 (32-col strip)
    const int grp  = blockIdx.x & 7;    // row group
    const int nt   = blockIdx.x >> 3;   // 0..31 col slice
    const int l15  = lane & 15;
    const int p    = l15 & 3;
    const int klo  = (lane >> 4) << 4;

    // ---- persistent B load (once): rows (nt&1)*64..+64 of itile nt>>1 ----
    {
        const char* src = (const char*)g_Ws + (size_t)(nt >> 1)*12*16384
                        + (size_t)(nt & 1)*64*128;
        #pragma unroll
        for (int it = 0; it < 12; ++it) {
            int c = wv*12 + it;             // 0..95 chunks of 1KB
            int kt = c >> 3, cc = c & 7;
            __builtin_amdgcn_global_load_lds(
                (gu32*)(src + (size_t)kt*16384 + cc*1024 + lane*16),
                (lu32*)(Bb + c*1024 + lane*16), 16, 0, 0);
        }
    }
    float4 bs4[2];
    #pragma unroll
    for (int n = 0; n < 2; ++n)
        bs4[n] = *(const float4*)&g_bsum[nt*64 + ng*32 + n*16 + (l15 >> 2)*4];

    float creg[2][2];
    #pragma unroll
    for (int m = 0; m < 2; ++m)
        #pragma unroll
        for (int n = 0; n < 2; ++n) creg[m][n] = 0.0f;

    asm volatile("s_waitcnt vmcnt(0)" ::: "memory");
    __syncthreads();

    auto stageA = [&](int t_, int kt_, int slot) {
        char* dst = As + slot*16384;
        #pragma unroll
        for (int it = 0; it < 2; ++it) {
            int c = wv*2 + it;              // 0..15 chunks of 1KB
            int sub = c >> 3, cc = c & 7;
            const char* src = (kt_ < 4)
                ? (const char*)g_Xs + (size_t)((t_*16 + grp*2 + sub)*4 + kt_)*8192
                : (const char*)g_Hh + (size_t)((t_*16 + grp*2 + sub)*8 + (kt_-4))*8192;
            __builtin_amdgcn_global_load_lds(
                (gu32*)(src + cc*1024 + lane*16),
                (lu32*)(dst + c*1024 + lane*16), 16, 0, 0);
        }
    };

    // prologue: X(0) kt0 -> S0, kt1 -> S1
    stageA(0, 0, 0);
    stageA(0, 1, 1);

    #pragma unroll 1
    for (int t = 0; t < 127; ++t) {
        stageA(t, 2, 2);
        stageA(t, 3, 3);
        f32x4 acc[2][2];
        #pragma unroll
        for (int m = 0; m < 2; ++m)
            #pragma unroll
            for (int n = 0; n < 2; ++n) acc[m][n] = (f32x4){0.f,0.f,0.f,0.f};

        #pragma unroll
        for (int kt = 0; kt < 12; ++kt) {
            if (kt == 2)      asm volatile("s_waitcnt vmcnt(2)\n\ts_barrier" ::: "memory");
            else if (kt == 3) asm volatile("s_waitcnt vmcnt(0)\n\ts_barrier" ::: "memory");
            else              asm volatile("s_waitcnt vmcnt(4)\n\ts_barrier" ::: "memory");
            const char* Ar = As + (kt & 3)*16384;
            const char* Br = Bb + kt*8192;
            #pragma unroll
            for (int kkl = 0; kkl < 2; ++kkl) {
                const int kb = kkl*64 + klo;
                f16x8 a[2], b[2];
                #pragma unroll
                for (int m = 0; m < 2; ++m) {
                    int r = mg*32 + m*16 + l15;
                    a[m] = *(const f16x8*)(Ar + (r >> 6)*8192 + (r & 63)*128
                                           + (kb ^ ((r & 7) << 4)));
                }
                #pragma unroll
                for (int n = 0; n < 2; ++n) {
                    int r = ng*32 + n*16 + l15;
                    b[n] = *(const f16x8*)(Br + r*128 + (kb ^ ((r & 7) << 4)));
                }
                #pragma unroll
                for (int m = 0; m < 2; ++m)
                    #pragma unroll
                    for (int n = 0; n < 2; ++n)
                        acc[m][n] = __builtin_amdgcn_mfma_f32_16x16x32_f16(
                            a[m], b[n], acc[m][n], 0, 0, 0);
            }
            // end-of-kt staging (slot (kt+3)%4: last read kt-1, covered by
            // this kt's top barrier)
            if (kt == 3) {
                bar_wait(grp, (unsigned)t);        // h(t) visible
                stageA(t, 4, 0); stageA(t, 5, 1); stageA(t, 6, 2);
            }
            if (kt == 4)  stageA(t, 7, 3);
            if (kt == 5)  stageA(t, 8, 0);
            if (kt == 6)  stageA(t, 9, 1);
            if (kt == 7)  stageA(t, 10, 2);
            if (kt == 8)  stageA(t, 11, 3);
            if (kt == 9)  stageA(t + 1, 0, 0);     // X(t+1); g_Xs padded
            if (kt == 10) stageA(t + 1, 1, 1);
        }

        // epilogue: barrier (all waves done reading slot3) -> transpose ->
        // cell update -> Hs (aliases slot3) -> coalesced 8B/thread store
        asm volatile("s_barrier" ::: "memory");
        #pragma unroll
        for (int m = 0; m < 2; ++m)
            #pragma unroll
            for (int n = 0; n < 2; ++n) {
                float v0 = acc[m][n][0], v1 = acc[m][n][1];
                float v2 = acc[m][n][2], v3 = acc[m][n][3];
                float s, r;
                s = (p & 1) ? v0 : v1; r = __shfl_xor(s, 1); if (p & 1) v0 = r; else v1 = r;
                s = (p & 1) ? v2 : v3; r = __shfl_xor(s, 1); if (p & 1) v2 = r; else v3 = r;
                s = (p & 2) ? v0 : v2; r = __shfl_xor(s, 2); if (p & 2) v0 = r; else v2 = r;
                s = (p & 2) ? v1 : v3; r = __shfl_xor(s, 2); if (p & 2) v1 = r; else v3 = r;
                float iv = fsigm(v0 + bs4[n].x);
                float fv = fsigm(v1 + bs4[n].y);
                float gg = ftanh(v2 + bs4[n].z);
                float ov = fsigm(v3 + bs4[n].w);
                float cv = fv * creg[m][n] + iv * gg;
                creg[m][n] = cv;
                float hv = ov * ftanh(cv);
                int rowl = mg*32 + m*16 + ((lane >> 4) << 2) + p;   // 0..127
                int coll = ng*8 + n*4 + (l15 >> 2);                 // 0..15
                Hs[rowl][coll] = (f16)hv;
            }
        __syncthreads();
        {
            char* hout = (char*)g_Hh + (size_t)(t + 1)*16*8*8192;
            int rowl = tid >> 2, q = tid & 3;
            int row = grp*128 + rowl;
            int jg  = nt*16 + q*4;
            f16x4 hv4 = *(const f16x4*)(&Hs[rowl][q*4]);
            char* hd = hout + (size_t)((row >> 6)*8 + (jg >> 6))*8192
                     + (row & 63)*128 + (((jg & 63)*2) ^ ((row & 7) << 4));
            *(f16x4*)hd = hv4;
        }
        bar_arrive(grp, (unsigned)(t + 1));   // its __syncthreads drains stores
    }
}

// ---------------------------------------------------------------------------
// mlp_all: batched 3-layer MLP for ALL tokens (round-4 proven structure).
// Block bi: tok = 1 + bi/16 (reads g_Hh[tok]), rows [mt*64,+64), mt = bi&15.
// ---------------------------------------------------------------------------
__global__ __launch_bounds__(256) void mlp_all(
    const float* __restrict__ b1, const float* __restrict__ b2,
    const float* __restrict__ b3, float* __restrict__ out)
{
    __shared__ char lds[65536];
    char* Wb = lds;            // 2 x 16384
    char* Ab = lds + 32768;    // 2 x 8192 (later Z2)
    char* Z1 = lds + 49152;    // 16384
    const int tid  = threadIdx.x;
    const int lane = tid & 63;
    const int w    = tid >> 6;
    const int bi   = blockIdx.x;
    const int tok  = 1 + (bi >> 4);
    const int mt   = bi & 15;
    const char* gH = (const char*)g_Hh + (size_t)(tok*16 + mt)*8*8192;
    float* outb = out + (size_t)(mt*64)*LE + (size_t)tok*E;

    float b1v[2], b2v[2], b3v[2][2];
    #pragma unroll
    for (int n = 0; n < 2; ++n) {
        int col = w*32 + n*16 + (lane & 15);
        b1v[n] = b1[col]; b2v[n] = b2[col];
        b3v[0][n] = b3[col]; b3v[1][n] = b3[128 + col];
    }
    const int kb0_0 = ((lane >> 4) << 4);

    f32x4 acc[4][2];
    #pragma unroll
    for (int m = 0; m < 4; ++m) { acc[m][0] = (f32x4){0,0,0,0}; acc[m][1] = (f32x4){0,0,0,0}; }

    #pragma unroll
    for (int it = 0; it < 2; ++it) {
        int c = w*2 + it;
        __builtin_amdgcn_global_load_lds((gu32*)(gH + c*1024 + lane*16),
                                         (lu32*)(Ab + c*1024 + lane*16), 16, 0, 0);
    }
    #pragma unroll
    for (int it = 0; it < 4; ++it) {
        int c = w*4 + it;
        __builtin_amdgcn_global_load_lds((gu32*)((const char*)g_W1s + c*1024 + lane*16),
                                         (lu32*)(Wb + c*1024 + lane*16), 16, 0, 0);
    }
    __syncthreads();

    for (int kt = 0; kt < 8; ++kt) {
        const int cur = kt & 1;
        if (kt < 7) {
            const char* gA = gH + (size_t)(kt+1)*8192;
            const char* gW = (const char*)g_W1s + (size_t)(kt+1)*16384;
            char* dA = Ab + (cur^1)*8192;
            char* dW = Wb + (cur^1)*16384;
            #pragma unroll
            for (int it = 0; it < 2; ++it) {
                int c = w*2 + it;
                __builtin_amdgcn_global_load_lds((gu32*)(gA + c*1024 + lane*16),
                                                 (lu32*)(dA + c*1024 + lane*16), 16, 0, 0);
            }
            #pragma unroll
            for (int it = 0; it < 4; ++it) {
                int c = w*4 + it;
                __builtin_amdgcn_global_load_lds((gu32*)(gW + c*1024 + lane*16),
                                                 (lu32*)(dW + c*1024 + lane*16), 16, 0, 0);
            }
        }
        const char* Ar = Ab + cur*8192;
        const char* Br = Wb + cur*16384;
        #pragma unroll
        for (int kk = 0; kk < 2; ++kk) {
            const int kb0 = kk*64 + kb0_0;
            f16x8 a[4], b[2];
            #pragma unroll
            for (int m = 0; m < 4; ++m) {
                int ar = m*16 + (lane & 15);
                a[m] = *(const f16x8*)(Ar + ar*128 + (kb0 ^ ((ar & 7) << 4)));
            }
            #pragma unroll
            for (int n = 0; n < 2; ++n) {
                int br = w*32 + n*16 + (lane & 15);
                b[n] = *(const f16x8*)(Br + br*128 + (kb0 ^ ((br & 7) << 4)));
            }
            #pragma unroll
            for (int m = 0; m < 4; ++m)
                #pragma unroll
                for (int n = 0; n < 2; ++n)
                    acc[m][n] = __builtin_amdgcn_mfma_f32_16x16x32_f16(a[m], b[n], acc[m][n], 0, 0, 0);
        }
        __syncthreads();
    }

    #pragma unroll
    for (int m = 0; m < 4; ++m)
        #pragma unroll
        for (int n = 0; n < 2; ++n)
            #pragma unroll
            for (int i = 0; i < 4; ++i) {
                int row = m*16 + ((lane >> 4) << 2) + i;
                int col = w*32 + n*16 + (lane & 15);
                float v = fmaxf(acc[m][n][i] + b1v[n], 0.0f);
                *(f16*)(Z1 + (col >> 6)*8192 + row*128
                        + (((col & 63)*2) ^ ((row & 7) << 4))) = (f16)v;
            }
    __syncthreads();

    #pragma unroll
    for (int it = 0; it < 8; ++it) {
        int c = w*8 + it;
        __builtin_amdgcn_global_load_lds((gu32*)((const char*)g_W2s + c*1024 + lane*16),
                                         (lu32*)(Wb + c*1024 + lane*16), 16, 0, 0);
    }
    __syncthreads();
    #pragma unroll
    for (int m = 0; m < 4; ++m) { acc[m][0] = (f32x4){0,0,0,0}; acc[m][1] = (f32x4){0,0,0,0}; }
    #pragma unroll
    for (int kt = 0; kt < 2; ++kt)
        #pragma unroll
        for (int kk = 0; kk < 2; ++kk) {
            const int kb0 = kk*64 + kb0_0;
            f16x8 a[4], b[2];
            #pragma unroll
            for (int m = 0; m < 4; ++m) {
                int ar = m*16 + (lane & 15);
                a[m] = *(const f16x8*)(Z1 + kt*8192 + ar*128 + (kb0 ^ ((ar & 7) << 4)));
            }
            #pragma unroll
            for (int n = 0; n < 2; ++n) {
                int br = w*32 + n*16 + (lane & 15);
                b[n] = *(const f16x8*)(Wb + kt*16384 + br*128 + (kb0 ^ ((br & 7) << 4)));
            }
            #pragma unroll
            for (int m = 0; m < 4; ++m)
                #pragma unroll
                for (int n = 0; n < 2; ++n)
                    acc[m][n] = __builtin_amdgcn_mfma_f32_16x16x32_f16(a[m], b[n], acc[m][n], 0, 0, 0);
        }
    __syncthreads();

    #pragma unroll
    for (int m = 0; m < 4; ++m)
        #pragma unroll
        for (int n = 0; n < 2; ++n)
            #pragma unroll
            for (int i = 0; i < 4; ++i) {
                int row = m*16 + ((lane >> 4) << 2) + i;
                int col = w*32 + n*16 + (lane & 15);
                float v = fmaxf(acc[m][n][i] + b2v[n], 0.0f);
                *(f16*)(Ab + (col >> 6)*8192 + row*128
                        + (((col & 63)*2) ^ ((row & 7) << 4))) = (f16)v;
            }
    __syncthreads();

    #pragma unroll
    for (int nh = 0; nh < 2; ++nh) {
        #pragma unroll
        for (int it = 0; it < 8; ++it) {
            int c = w*8 + it;
            __builtin_amdgcn_global_load_lds(
                (gu32*)((const char*)g_W3s + (size_t)nh*32768 + c*1024 + lane*16),
                (lu32*)(Wb + c*1024 + lane*16), 16, 0, 0);
        }
        __syncthreads();
        #pragma unroll
        for (int m = 0; m < 4; ++m) { acc[m][0] = (f32x4){0,0,0,0}; acc[m][1] = (f32x4){0,0,0,0}; }
        #pragma unroll
        for (int kt = 0; kt < 2; ++kt)
            #pragma unroll
            for (int kk = 0; kk < 2; ++kk) {
                const int kb0 = kk*64 + kb0_0;
                f16x8 a[4], b[2];
                #pragma unroll
                for (int m = 0; m < 4; ++m) {
                    int ar = m*16 + (lane & 15);
                    a[m] = *(const f16x8*)(Ab + kt*8192 + ar*128 + (kb0 ^ ((ar & 7) << 4)));
                }
                #pragma unroll
                for (int n = 0; n < 2; ++n) {
                    int br = w*32 + n*16 + (lane & 15);
                    b[n] = *(const f16x8*)(Wb + kt*16384 + br*128 + (kb0 ^ ((br & 7) << 4)));
                }
                #pragma unroll
                for (int m = 0; m < 4; ++m)
                    #pragma unroll
                    for (int n = 0; n < 2; ++n)
                        acc[m][n] = __builtin_amdgcn_mfma_f32_16x16x32_f16(a[m], b[n], acc[m][n], 0, 0, 0);
            }
        #pragma unroll
        for (int m = 0; m < 4; ++m)
            #pragma unroll
            for (int n = 0; n < 2; ++n)
                #pragma unroll
                for (int i = 0; i < 4; ++i) {
                    int row = m*16 + ((lane >> 4) << 2) + i;
                    int col = nh*128 + w*32 + n*16 + (lane & 15);
                    outb[(size_t)row*LE + col] = acc[m][n][i] + b3v[nh][n];
                }
        __syncthreads();
    }
}

// ---------------------------------------------------------------------------
extern "C" void kernel_launch(void* const* d_in, const int* in_sizes, int n_in,
                              void* d_out, int out_size, void* d_ws, size_t ws_size,
                              hipStream_t stream) {
    (void)in_sizes; (void)n_in; (void)out_size; (void)d_ws; (void)ws_size;
    const float* hidden = (const float*)d_in[0];
    const float* padded = (const float*)d_in[1];
    const float* W_ih   = (const float*)d_in[2];
    const float* W_hh   = (const float*)d_in[3];
    const float* b_ih   = (const float*)d_in[4];
    const float* b_hh   = (const float*)d_in[5];
    const float* W1     = (const float*)d_in[6];
    const float* b1     = (const float*)d_in[7];
    const float* W2     = (const float*)d_in[8];
    const float* b2     = (const float*)d_in[9];
    const float* W3     = (const float*)d_in[10];
    const float* b3     = (const float*)d_in[11];
    float* out = (float*)d_out;

    conv_w<<<768, 256, 0, stream>>>(W_ih, W_hh, b_ih, b_hh);
    conv_mlp<<<56, 256, 0, stream>>>(W1, W2, W3);
    conv_x<<<16256, 256, 0, stream>>>(padded);
    init_kernel<<<2048, 256, 0, stream>>>(hidden, out);
    step_all<<<256, 512, 0, stream>>>();
    mlp_all<<<2032, 256, 0, stream>>>(b1, b2, b3, out);
}

// Round 11
// 1544.946 us; speedup vs baseline: 1.3551x; 1.3551x over previous
//
#include <hip/hip_runtime.h>
#include <math.h>
#include <stdint.h>

#define B 1024
#define H 512
#define E 256
#define L 128
#define LE (L*E)   // 32768

typedef _Float16 f16;
typedef _Float16 f16x8 __attribute__((ext_vector_type(8)));
typedef float f32x4 __attribute__((ext_vector_type(4)));
typedef const __attribute__((address_space(1))) uint32_t gu32;
typedef __attribute__((address_space(3))) uint32_t lu32;

// ---------------------------------------------------------------------------
// Persistent state in module device globals. Everything rewritten every call.
// ---------------------------------------------------------------------------
__device__ __align__(16) f16 g_Xs[128*16*4*4096];   // X images [t:128 pad][mt16][kt:4] 64x64
__device__ __align__(16) f16 g_Hh[128*16*8*4096];   // h(t) images, t=0..127 (134 MB)
__device__ __align__(16) f16 g_Ws[16*12*8192];      // gates W' [itile:16][kt:12] 128x64
__device__ __align__(16) f16 g_W1s[8*8192];         // W1' [kt:8] 128x64
__device__ __align__(16) f16 g_W2s[2*8192];         // W2' [kt:2] 128x64
__device__ __align__(16) f16 g_W3s[4*8192];         // W3' [nh:2][kt:2] 128x64
__device__ __align__(16) float g_bsum[2048];        // b_ih+b_hh, n=j*4+g order

// Flag-array barrier: 8 groups x 32 flags, one cacheline each. NO atomic RMW:
// arrival = release-store own flag; wait = 32 parallel relaxed polls + one
// acquire load. (Round-10 lesson: 32 serialized fetch_adds on one line were
// ~5us/step at the coherence point.)
struct __align__(128) Flag { unsigned int v; unsigned int pad[31]; };
__device__ Flag g_flags[8][32];

__device__ __forceinline__ void bar_arrive(int g, int idx, unsigned int target) {
    __syncthreads();   // all h stores issued (vmcnt drained by caller)
    if (threadIdx.x == 0)
        __hip_atomic_store(&g_flags[g][idx].v, target,
                           __ATOMIC_RELEASE, __HIP_MEMORY_SCOPE_AGENT);
}
__device__ __forceinline__ void bar_wait(int g, unsigned int target) {
    if (threadIdx.x < 64) {
        const int f = threadIdx.x & 31;       // lanes 32..63 mirror 0..31
        for (;;) {
            unsigned int v = __hip_atomic_load(&g_flags[g][f].v,
                               __ATOMIC_RELAXED, __HIP_MEMORY_SCOPE_AGENT);
            if (__all(v >= target)) break;
            __builtin_amdgcn_s_sleep(1);
        }
        if (threadIdx.x == 0)
            (void)__hip_atomic_load(&g_flags[g][0].v,
                    __ATOMIC_ACQUIRE, __HIP_MEMORY_SCOPE_AGENT);
    }
    __syncthreads();
}

__device__ __forceinline__ float fsigm(float x) {
    return __builtin_amdgcn_rcpf(1.0f + __expf(-x));
}
__device__ __forceinline__ float ftanh(float x) {
    return 2.0f * __builtin_amdgcn_rcpf(1.0f + __expf(-2.0f * x)) - 1.0f;
}

// ---------------------------------------------------------------------------
// conv_w: gates W' fp16 tile images (gate-interleaved n=j*4+g) + bias sums
// ---------------------------------------------------------------------------
__global__ __launch_bounds__(256) void conv_w(
    const float* __restrict__ W_ih, const float* __restrict__ W_hh,
    const float* __restrict__ b_ih, const float* __restrict__ b_hh)
{
    int gid = blockIdx.x*256 + threadIdx.x;   // 196608
    int kb  = gid & 7;
    int r1  = gid >> 3;
    int row = r1 & 127;
    int r2  = r1 >> 7;
    int kt  = r2 % 12;
    int nt  = r2 / 12;
    int n = nt*128 + row;
    int g = n & 3, j = n >> 2;
    int wrow = g*512 + j;
    int k = kt*64 + kb*8;
    const float* src = (k < 256) ? (W_ih + wrow*256 + k)
                                 : (W_hh + wrow*512 + (k - 256));
    f16x8 v;
    #pragma unroll
    for (int e = 0; e < 8; ++e) v[e] = (f16)src[e];
    char* dst = (char*)g_Ws + (size_t)(nt*12 + kt)*16384
              + row*128 + ((kb*16) ^ ((row & 7) << 4));
    *(f16x8*)dst = v;
    if (gid < 2048) {
        int gg = gid & 3, jj = gid >> 2;
        g_bsum[gid] = b_ih[gg*512 + jj] + b_hh[gg*512 + jj];
    }
}

// ---------------------------------------------------------------------------
// conv_mlp: W1/W2/W3 fp16 tile images
// ---------------------------------------------------------------------------
__global__ __launch_bounds__(256) void conv_mlp(
    const float* __restrict__ W1, const float* __restrict__ W2,
    const float* __restrict__ W3)
{
    int gid = blockIdx.x*256 + threadIdx.x;   // 14336
    if (gid < 8192) {                         // W1 (128,512) -> 8 tiles
        int s = gid;
        int kb = s & 7, row = (s >> 3) & 127, kt = s >> 10;
        const float* src = W1 + row*512 + kt*64 + kb*8;
        f16x8 v;
        #pragma unroll
        for (int e = 0; e < 8; ++e) v[e] = (f16)src[e];
        char* dst = (char*)g_W1s + (size_t)kt*16384
                  + row*128 + ((kb*16) ^ ((row & 7) << 4));
        *(f16x8*)dst = v;
    } else if (gid < 10240) {                 // W2 (128,128) -> 2 tiles
        int s = gid - 8192;
        int kb = s & 7, row = (s >> 3) & 127, kt = s >> 10;
        const float* src = W2 + row*128 + kt*64 + kb*8;
        f16x8 v;
        #pragma unroll
        for (int e = 0; e < 8; ++e) v[e] = (f16)src[e];
        char* dst = (char*)g_W2s + (size_t)kt*16384
                  + row*128 + ((kb*16) ^ ((row & 7) << 4));
        *(f16x8*)dst = v;
    } else if (gid < 14336) {                 // W3 (256,128) -> [nh:2][kt:2]
        int s = gid - 10240;
        int kb = s & 7, r256 = (s >> 3) & 255, kt = s >> 11;
        int nh = r256 >> 7, row = r256 & 127;
        const float* src = W3 + r256*128 + kt*64 + kb*8;
        f16x8 v;
        #pragma unroll
        for (int e = 0; e < 8; ++e) v[e] = (f16)src[e];
        char* dst = (char*)g_W3s + (size_t)(nh*2 + kt)*16384
                  + row*128 + ((kb*16) ^ ((row & 7) << 4));
        *(f16x8*)dst = v;
    }
}

// ---------------------------------------------------------------------------
// conv_x: X fp16 tile images (coalesced: 32 consecutive lanes = 1 KB)
// ---------------------------------------------------------------------------
__global__ __launch_bounds__(256) void conv_x(const float* __restrict__ padded)
{
    int gid = blockIdx.x*256 + threadIdx.x;   // 127*1024*32 = 4161536 exact
    int kq = gid & 31;
    int b  = (gid >> 5) & 1023;
    int t  = gid >> 15;
    const float* src = padded + (size_t)b*LE + t*E + kq*8;
    float4 v0 = *(const float4*)src;
    float4 v1 = *(const float4*)(src + 4);
    f16x8 v;
    v[0]=(f16)v0.x; v[1]=(f16)v0.y; v[2]=(f16)v0.z; v[3]=(f16)v0.w;
    v[4]=(f16)v1.x; v[5]=(f16)v1.y; v[6]=(f16)v1.z; v[7]=(f16)v1.w;
    int kt = kq >> 3, kb = kq & 7;
    int row = b & 63, mt16 = b >> 6;
    char* dst = (char*)g_Xs + (size_t)((t*16 + mt16)*4 + kt)*8192
              + row*128 + ((kb*16) ^ ((row & 7) << 4));
    *(f16x8*)dst = v;
}

// ---------------------------------------------------------------------------
// init: g_Hh[0] <- hidden image, out row 0 <- one-hot, flags reset
// ---------------------------------------------------------------------------
__global__ __launch_bounds__(256) void init_kernel(
    const float* __restrict__ hidden, float* __restrict__ out)
{
    int i = blockIdx.x * 256 + threadIdx.x;
    if (i < 256) g_flags[i >> 5][i & 31].v = 0u;
    if (i < B*H) {
        float hv = hidden[i];
        int b = i >> 9, j = i & 511;
        int mt = b >> 6, row = b & 63, kt = j >> 6, kk = j & 63;
        char* dst = (char*)g_Hh + (size_t)(mt*8 + kt)*8192
                  + row*128 + ((kk*2) ^ ((row & 7) << 4));
        *(f16*)dst = (f16)hv;
    }
    if (i < B*E) {
        int b = i >> 8, e = i & 255;
        out[b*LE + e] = (e == 0) ? 1.0f : 0.0f;
    }
}

// ---------------------------------------------------------------------------
// step_all: persistent gates recurrence, 8 groups of 32 blocks, 256 threads
// (round-9 winner config). Group (blockIdx&7) owns rows [g*128,+128); block
// owns gate-cols [nt*64,+64). B (96 KB) persistent; A in 4 rotating 16 KB
// slots -> ONE barrier per kt. vmcnt: kt0->12, kt1->8, kt2->4, kt3->0
// (drain before group-wait), kt>=4 -> 8. Flag-array group barrier.
// ---------------------------------------------------------------------------
__global__ __launch_bounds__(256, 1) void step_all()
{
    __shared__ __align__(16) char lds[163840];
    char* Bb = lds;                                   // 12 x 8192 persistent B
    char* As = lds + 98304;                           // 4 x 16384 A slots
    f16 (*Hs)[16] = (f16 (*)[16])(As + 3*16384);      // aliases slot3

    const int tid  = threadIdx.x;
    const int lane = tid & 63;
    const int wv   = tid >> 6;          // 0..3 (32-row strip)
    const int grp  = blockIdx.x & 7;    // row group (XCD-local heuristic)
    const int nt   = blockIdx.x >> 3;   // 0..31 col slice
    const int l15  = lane & 15;
    const int p    = l15 & 3;
    const int klo  = (lane >> 4) << 4;

    // ---- persistent B load (once): rows (nt&1)*64..+64 of itile nt>>1 ----
    {
        const char* src = (const char*)g_Ws + (size_t)(nt >> 1)*12*16384
                        + (size_t)(nt & 1)*64*128;
        #pragma unroll
        for (int it = 0; it < 24; ++it) {
            int c = wv*24 + it;             // 0..95 chunks of 1KB
            int kt = c >> 3, cc = c & 7;
            __builtin_amdgcn_global_load_lds(
                (gu32*)(src + (size_t)kt*16384 + cc*1024 + lane*16),
                (lu32*)(Bb + c*1024 + lane*16), 16, 0, 0);
        }
    }
    float4 bs4[4];
    #pragma unroll
    for (int n = 0; n < 4; ++n)
        bs4[n] = *(const float4*)&g_bsum[nt*64 + n*16 + (l15 >> 2)*4];

    float creg[2][4];
    #pragma unroll
    for (int m = 0; m < 2; ++m)
        #pragma unroll
        for (int n = 0; n < 4; ++n) creg[m][n] = 0.0f;

    asm volatile("s_waitcnt vmcnt(0)" ::: "memory");
    __syncthreads();

    auto stageA = [&](int t_, int kt_, int slot) {
        char* dst = As + slot*16384;
        #pragma unroll
        for (int it = 0; it < 4; ++it) {
            int c = wv*4 + it;              // 0..15 chunks of 1KB (16 KB)
            int sub = c >> 3, cc = c & 7;
            const char* src = (kt_ < 4)
                ? (const char*)g_Xs + (size_t)((t_*16 + grp*2 + sub)*4 + kt_)*8192
                : (const char*)g_Hh + (size_t)((t_*16 + grp*2 + sub)*8 + (kt_-4))*8192;
            __builtin_amdgcn_global_load_lds(
                (gu32*)(src + cc*1024 + lane*16),
                (lu32*)(dst + c*1024 + lane*16), 16, 0, 0);
        }
    };

    // prologue: X(0) kt0 -> S0, kt1 -> S1
    stageA(0, 0, 0);
    stageA(0, 1, 1);

    #pragma unroll 1
    for (int t = 0; t < 127; ++t) {
        stageA(t, 2, 2);
        stageA(t, 3, 3);
        f32x4 acc[2][4];
        #pragma unroll
        for (int m = 0; m < 2; ++m)
            #pragma unroll
            for (int n = 0; n < 4; ++n) acc[m][n] = (f32x4){0.f,0.f,0.f,0.f};

        #pragma unroll
        for (int kt = 0; kt < 12; ++kt) {
            // ONE barrier per kt: wait this kt's stage, sync slot reuse
            if (kt == 0)      asm volatile("s_waitcnt vmcnt(12)\n\ts_barrier" ::: "memory");
            else if (kt == 1) asm volatile("s_waitcnt vmcnt(8)\n\ts_barrier" ::: "memory");
            else if (kt == 2) asm volatile("s_waitcnt vmcnt(4)\n\ts_barrier" ::: "memory");
            else if (kt == 3) asm volatile("s_waitcnt vmcnt(0)\n\ts_barrier" ::: "memory");
            else              asm volatile("s_waitcnt vmcnt(8)\n\ts_barrier" ::: "memory");
            const char* Ar = As + (kt & 3)*16384;
            const char* Br = Bb + kt*8192;
            #pragma unroll
            for (int kkl = 0; kkl < 2; ++kkl) {
                const int kb = kkl*64 + klo;
                f16x8 a[2], b[4];
                #pragma unroll
                for (int m = 0; m < 2; ++m) {
                    int r = wv*32 + m*16 + l15;
                    a[m] = *(const f16x8*)(Ar + (r >> 6)*8192 + (r & 63)*128
                                           + (kb ^ ((r & 7) << 4)));
                }
                #pragma unroll
                for (int n = 0; n < 4; ++n) {
                    int r = n*16 + l15;
                    b[n] = *(const f16x8*)(Br + r*128 + (kb ^ ((r & 7) << 4)));
                }
                #pragma unroll
                for (int m = 0; m < 2; ++m)
                    #pragma unroll
                    for (int n = 0; n < 4; ++n)
                        acc[m][n] = __builtin_amdgcn_mfma_f32_16x16x32_f16(
                            a[m], b[n], acc[m][n], 0, 0, 0);
            }
            // end-of-kt staging: slot (kt+3)%4, last read at kt-1 (covered by
            // this kt's top barrier)
            if (kt == 3) {
                bar_wait(grp, (unsigned)t);        // h(t) visible
                stageA(t, 4, 0); stageA(t, 5, 1); stageA(t, 6, 2);
            }
            if (kt == 4)  stageA(t, 7, 3);
            if (kt == 5)  stageA(t, 8, 0);
            if (kt == 6)  stageA(t, 9, 1);
            if (kt == 7)  stageA(t, 10, 2);
            if (kt == 8)  stageA(t, 11, 3);
            if (kt == 9)  stageA(t + 1, 0, 0);     // X(t+1); g_Xs padded
            if (kt == 10) stageA(t + 1, 1, 1);
        }

        // epilogue: barrier (slot3 reads consumed by kt11's MFMAs) ->
        // transpose -> cell update -> Hs (aliases slot3) -> coalesced store
        asm volatile("s_barrier" ::: "memory");
        #pragma unroll
        for (int m = 0; m < 2; ++m)
            #pragma unroll
            for (int n = 0; n < 4; ++n) {
                float v0 = acc[m][n][0], v1 = acc[m][n][1];
                float v2 = acc[m][n][2], v3 = acc[m][n][3];
                float s, r;
                s = (p & 1) ? v0 : v1; r = __shfl_xor(s, 1); if (p & 1) v0 = r; else v1 = r;
                s = (p & 1) ? v2 : v3; r = __shfl_xor(s, 1); if (p & 1) v2 = r; else v3 = r;
                s = (p & 2) ? v0 : v2; r = __shfl_xor(s, 2); if (p & 2) v0 = r; else v2 = r;
                s = (p & 2) ? v1 : v3; r = __shfl_xor(s, 2); if (p & 2) v1 = r; else v3 = r;
                float iv = fsigm(v0 + bs4[n].x);
                float fv = fsigm(v1 + bs4[n].y);
                float gg = ftanh(v2 + bs4[n].z);
                float ov = fsigm(v3 + bs4[n].w);
                float cv = fv * creg[m][n] + iv * gg;
                creg[m][n] = cv;
                float hv = ov * ftanh(cv);
                int rowl = wv*32 + m*16 + ((lane >> 4) << 2) + p;   // 0..127
                int coll = n*4 + (l15 >> 2);                        // 0..15
                Hs[rowl][coll] = (f16)hv;
            }
        __syncthreads();
        // coalesced h store: ONE 16B store per thread
        {
            char* hout = (char*)g_Hh + (size_t)(t + 1)*16*8*8192;
            int rowl = tid >> 1, half = tid & 1;
            int row = grp*128 + rowl;
            int jg  = nt*16 + half*8;
            f16x8 hv8 = *(const f16x8*)(&Hs[rowl][half*8]);
            char* hd = hout + (size_t)((row >> 6)*8 + (jg >> 6))*8192
                     + (row & 63)*128 + (((jg & 63)*2) ^ ((row & 7) << 4));
            *(f16x8*)hd = hv8;
        }
        asm volatile("s_waitcnt vmcnt(0)" ::: "memory");  // drain h stores
        bar_arrive(grp, nt, (unsigned)(t + 1));
    }
}

// ---------------------------------------------------------------------------
// mlp_all: batched 3-layer MLP for ALL tokens (round-4 proven structure).
// Block bi: tok = 1 + bi/16 (reads g_Hh[tok]), rows [mt*64,+64), mt = bi&15.
// ---------------------------------------------------------------------------
__global__ __launch_bounds__(256) void mlp_all(
    const float* __restrict__ b1, const float* __restrict__ b2,
    const float* __restrict__ b3, float* __restrict__ out)
{
    __shared__ char lds[65536];
    char* Wb = lds;            // 2 x 16384
    char* Ab = lds + 32768;    // 2 x 8192 (later Z2)
    char* Z1 = lds + 49152;    // 16384
    const int tid  = threadIdx.x;
    const int lane = tid & 63;
    const int w    = tid >> 6;
    const int bi   = blockIdx.x;
    const int tok  = 1 + (bi >> 4);
    const int mt   = bi & 15;
    const char* gH = (const char*)g_Hh + (size_t)(tok*16 + mt)*8*8192;
    float* outb = out + (size_t)(mt*64)*LE + (size_t)tok*E;

    float b1v[2], b2v[2], b3v[2][2];
    #pragma unroll
    for (int n = 0; n < 2; ++n) {
        int col = w*32 + n*16 + (lane & 15);
        b1v[n] = b1[col]; b2v[n] = b2[col];
        b3v[0][n] = b3[col]; b3v[1][n] = b3[128 + col];
    }
    const int kb0_0 = ((lane >> 4) << 4);

    f32x4 acc[4][2];
    #pragma unroll
    for (int m = 0; m < 4; ++m) { acc[m][0] = (f32x4){0,0,0,0}; acc[m][1] = (f32x4){0,0,0,0}; }

    #pragma unroll
    for (int it = 0; it < 2; ++it) {
        int c = w*2 + it;
        __builtin_amdgcn_global_load_lds((gu32*)(gH + c*1024 + lane*16),
                                         (lu32*)(Ab + c*1024 + lane*16), 16, 0, 0);
    }
    #pragma unroll
    for (int it = 0; it < 4; ++it) {
        int c = w*4 + it;
        __builtin_amdgcn_global_load_lds((gu32*)((const char*)g_W1s + c*1024 + lane*16),
                                         (lu32*)(Wb + c*1024 + lane*16), 16, 0, 0);
    }
    __syncthreads();

    for (int kt = 0; kt < 8; ++kt) {
        const int cur = kt & 1;
        if (kt < 7) {
            const char* gA = gH + (size_t)(kt+1)*8192;
            const char* gW = (const char*)g_W1s + (size_t)(kt+1)*16384;
            char* dA = Ab + (cur^1)*8192;
            char* dW = Wb + (cur^1)*16384;
            #pragma unroll
            for (int it = 0; it < 2; ++it) {
                int c = w*2 + it;
                __builtin_amdgcn_global_load_lds((gu32*)(gA + c*1024 + lane*16),
                                                 (lu32*)(dA + c*1024 + lane*16), 16, 0, 0);
            }
            #pragma unroll
            for (int it = 0; it < 4; ++it) {
                int c = w*4 + it;
                __builtin_amdgcn_global_load_lds((gu32*)(gW + c*1024 + lane*16),
                                                 (lu32*)(dW + c*1024 + lane*16), 16, 0, 0);
            }
        }
        const char* Ar = Ab + cur*8192;
        const char* Br = Wb + cur*16384;
        #pragma unroll
        for (int kk = 0; kk < 2; ++kk) {
            const int kb0 = kk*64 + kb0_0;
            f16x8 a[4], b[2];
            #pragma unroll
            for (int m = 0; m < 4; ++m) {
                int ar = m*16 + (lane & 15);
                a[m] = *(const f16x8*)(Ar + ar*128 + (kb0 ^ ((ar & 7) << 4)));
            }
            #pragma unroll
            for (int n = 0; n < 2; ++n) {
                int br = w*32 + n*16 + (lane & 15);
                b[n] = *(const f16x8*)(Br + br*128 + (kb0 ^ ((br & 7) << 4)));
            }
            #pragma unroll
            for (int m = 0; m < 4; ++m)
                #pragma unroll
                for (int n = 0; n < 2; ++n)
                    acc[m][n] = __builtin_amdgcn_mfma_f32_16x16x32_f16(a[m], b[n], acc[m][n], 0, 0, 0);
        }
        __syncthreads();
    }

    #pragma unroll
    for (int m = 0; m < 4; ++m)
        #pragma unroll
        for (int n = 0; n < 2; ++n)
            #pragma unroll
            for (int i = 0; i < 4; ++i) {
                int row = m*16 + ((lane >> 4) << 2) + i;
                int col = w*32 + n*16 + (lane & 15);
                float v = fmaxf(acc[m][n][i] + b1v[n], 0.0f);
                *(f16*)(Z1 + (col >> 6)*8192 + row*128
                        + (((col & 63)*2) ^ ((row & 7) << 4))) = (f16)v;
            }
    __syncthreads();

    #pragma unroll
    for (int it = 0; it < 8; ++it) {
        int c = w*8 + it;
        __builtin_amdgcn_global_load_lds((gu32*)((const char*)g_W2s + c*1024 + lane*16),
                                         (lu32*)(Wb + c*1024 + lane*16), 16, 0, 0);
    }
    __syncthreads();
    #pragma unroll
    for (int m = 0; m < 4; ++m) { acc[m][0] = (f32x4){0,0,0,0}; acc[m][1] = (f32x4){0,0,0,0}; }
    #pragma unroll
    for (int kt = 0; kt < 2; ++kt)
        #pragma unroll
        for (int kk = 0; kk < 2; ++kk) {
            const int kb0 = kk*64 + kb0_0;
            f16x8 a[4], b[2];
            #pragma unroll
            for (int m = 0; m < 4; ++m) {
                int ar = m*16 + (lane & 15);
                a[m] = *(const f16x8*)(Z1 + kt*8192 + ar*128 + (kb0 ^ ((ar & 7) << 4)));
            }
            #pragma unroll
            for (int n = 0; n < 2; ++n) {
                int br = w*32 + n*16 + (lane & 15);
                b[n] = *(const f16x8*)(Wb + kt*16384 + br*128 + (kb0 ^ ((br & 7) << 4)));
            }
            #pragma unroll
            for (int m = 0; m < 4; ++m)
                #pragma unroll
                for (int n = 0; n < 2; ++n)
                    acc[m][n] = __builtin_amdgcn_mfma_f32_16x16x32_f16(a[m], b[n], acc[m][n], 0, 0, 0);
        }
    __syncthreads();

    #pragma unroll
    for (int m = 0; m < 4; ++m)
        #pragma unroll
        for (int n = 0; n < 2; ++n)
            #pragma unroll
            for (int i = 0; i < 4; ++i) {
                int row = m*16 + ((lane >> 4) << 2) + i;
                int col = w*32 + n*16 + (lane & 15);
                float v = fmaxf(acc[m][n][i] + b2v[n], 0.0f);
                *(f16*)(Ab + (col >> 6)*8192 + row*128
                        + (((col & 63)*2) ^ ((row & 7) << 4))) = (f16)v;
            }
    __syncthreads();

    #pragma unroll
    for (int nh = 0; nh < 2; ++nh) {
        #pragma unroll
        for (int it = 0; it < 8; ++it) {
            int c = w*8 + it;
            __builtin_amdgcn_global_load_lds(
                (gu32*)((const char*)g_W3s + (size_t)nh*32768 + c*1024 + lane*16),
                (lu32*)(Wb + c*1024 + lane*16), 16, 0, 0);
        }
        __syncthreads();
        #pragma unroll
        for (int m = 0; m < 4; ++m) { acc[m][0] = (f32x4){0,0,0,0}; acc[m][1] = (f32x4){0,0,0,0}; }
        #pragma unroll
        for (int kt = 0; kt < 2; ++kt)
            #pragma unroll
            for (int kk = 0; kk < 2; ++kk) {
                const int kb0 = kk*64 + kb0_0;
                f16x8 a[4], b[2];
                #pragma unroll
                for (int m = 0; m < 4; ++m) {
                    int ar = m*16 + (lane & 15);
                    a[m] = *(const f16x8*)(Ab + kt*8192 + ar*128 + (kb0 ^ ((ar & 7) << 4)));
                }
                #pragma unroll
                for (int n = 0; n < 2; ++n) {
                    int br = w*32 + n*16 + (lane & 15);
                    b[n] = *(const f16x8*)(Wb + kt*16384 + br*128 + (kb0 ^ ((br & 7) << 4)));
                }
                #pragma unroll
                for (int m = 0; m < 4; ++m)
                    #pragma unroll
                    for (int n = 0; n < 2; ++n)
                        acc[m][n] = __builtin_amdgcn_mfma_f32_16x16x32_f16(a[m], b[n], acc[m][n], 0, 0, 0);
            }
        #pragma unroll
        for (int m = 0; m < 4; ++m)
            #pragma unroll
            for (int n = 0; n < 2; ++n)
                #pragma unroll
                for (int i = 0; i < 4; ++i) {
                    int row = m*16 + ((lane >> 4) << 2) + i;
                    int col = nh*128 + w*32 + n*16 + (lane & 15);
                    outb[(size_t)row*LE + col] = acc[m][n][i] + b3v[nh][n];
                }
        __syncthreads();
    }
}

// ---------------------------------------------------------------------------
extern "C" void kernel_launch(void* const* d_in, const int* in_sizes, int n_in,
                              void* d_out, int out_size, void* d_ws, size_t ws_size,
                              hipStream_t stream) {
    (void)in_sizes; (void)n_in; (void)out_size; (void)d_ws; (void)ws_size;
    const float* hidden = (const float*)d_in[0];
    const float* padded = (const float*)d_in[1];
    const float* W_ih   = (const float*)d_in[2];
    const float* W_hh   = (const float*)d_in[3];
    const float* b_ih   = (const float*)d_in[4];
    const float* b_hh   = (const float*)d_in[5];
    const float* W1     = (const float*)d_in[6];
    const float* b1     = (const float*)d_in[7];
    const float* W2     = (const float*)d_in[8];
    const float* b2     = (const float*)d_in[9];
    const float* W3     = (const float*)d_in[10];
    const float* b3     = (const float*)d_in[11];
    float* out = (float*)d_out;

    conv_w<<<768, 256, 0, stream>>>(W_ih, W_hh, b_ih, b_hh);
    conv_mlp<<<56, 256, 0, stream>>>(W1, W2, W3);
    conv_x<<<16256, 256, 0, stream>>>(padded);
    init_kernel<<<2048, 256, 0, stream>>>(hidden, out);
    step_all<<<256, 256, 0, stream>>>();
    mlp_all<<<2032, 256, 0, stream>>>(b1, b2, b3, out);
}